// Round 1
// baseline (109.710 us; speedup 1.0000x reference)
//
#include <hip/hip_runtime.h>

#define BLOCK 256
#define CHUNK 16
#define SPAN (BLOCK * CHUNK)  // 4096 steps per block

// Affine transform x -> [[p,q],[r,s]] x + [u,v]
struct Xf { float p, q, r, s, u, v; };

__device__ __forceinline__ Xf xf_id() {
    Xf t; t.p = 1.f; t.q = 0.f; t.r = 0.f; t.s = 1.f; t.u = 0.f; t.v = 0.f;
    return t;
}

// result = L ∘ E  (E applied first, then L)
__device__ __forceinline__ Xf xf_compose(const Xf& E, const Xf& L) {
    Xf o;
    o.p = L.p * E.p + L.q * E.r;
    o.q = L.p * E.q + L.q * E.s;
    o.r = L.r * E.p + L.s * E.r;
    o.s = L.r * E.q + L.s * E.s;
    o.u = L.p * E.u + L.q * E.v + L.u;
    o.v = L.r * E.u + L.s * E.v + L.v;
    return o;
}

struct Par {
    float M11, M12, M21, Kx;   // fixed M entries, Kx = M12*M21
    float c0, c1;              // M22 = c0 + c1*rRia ; c1 = dt/C_in
    float cTo0, cIrr0, cQi0;   // bu0 coefficients
    float cIrr1, cQi1;         // bu1 coefficients (To,Qah use c1)
};

__device__ __forceinline__ Par make_par(
    const float* pRie, const float* pRea, const float* pCin, const float* pCen,
    const float* pAsi, const float* pAse, const float* pAii, const float* pAie)
{
    const float dt = 1800.0f;
    const float GA = 0.76f * 41.3f;  // g * Az
    float R_ie = *pRie, R_ea = *pRea, C_in = *pCin, C_en = *pCen;
    float asi = *pAsi, ase = *pAse, aii = *pAii, aie = *pAie;
    Par P;
    float iRie = 1.0f / R_ie;
    P.M11 = 1.0f + dt * (1.0f / R_ea + iRie) / C_en;
    P.M12 = -(dt * iRie) / C_en;
    P.M21 = -(dt * iRie) / C_in;
    P.Kx  = P.M12 * P.M21;
    P.c1  = dt / C_in;
    P.c0  = 1.0f + P.c1 * iRie;
    P.cTo0  = dt / (C_en * R_ea);
    P.cIrr0 = dt * ase * GA / C_en;
    P.cQi0  = dt * aie / C_en;
    P.cIrr1 = dt * asi * GA / C_in;
    P.cQi1  = dt * aii / C_in;
    return P;
}

__device__ __forceinline__ Xf gen_step(const Par& P, float To, float Irr,
                                       float Qi, float Qa, float Ra)
{
    float rR  = __builtin_amdgcn_rcpf(fmaxf(Ra, 1e-6f));
    float M22 = fmaf(P.c1, rR, P.c0);
    float det = fmaf(P.M11, M22, -P.Kx);
    float rd  = __builtin_amdgcn_rcpf(det);
    float bu0 = P.cTo0 * To + P.cIrr0 * Irr + P.cQi0 * Qi;
    float bu1 = P.c1 * fmaf(To, rR, Qa) + P.cIrr1 * Irr + P.cQi1 * Qi;
    Xf T;
    T.p =  M22 * rd;
    T.q = -P.M12 * rd;
    T.r = -P.M21 * rd;
    T.s =  P.M11 * rd;
    T.u = T.p * bu0 + T.q * bu1;
    T.v = T.r * bu0 + T.s * bu1;
    return T;
}

// Composed transform of one thread's CHUNK contiguous steps (identity-padded past N)
__device__ __forceinline__ Xf chunk_xf(const Par& P,
    const float* __restrict__ To, const float* __restrict__ Irr,
    const float* __restrict__ Qi, const float* __restrict__ Qa,
    const float* __restrict__ Ra, int base, int N)
{
    Xf v = xf_id();
    if (base + CHUNK <= N) {
#pragma unroll
        for (int g = 0; g < CHUNK / 4; ++g) {
            const int o = base + g * 4;
            float4 t  = *(const float4*)(To + o);
            float4 ir = *(const float4*)(Irr + o);
            float4 qi = *(const float4*)(Qi + o);
            float4 qa = *(const float4*)(Qa + o);
            float4 ra = *(const float4*)(Ra + o);
            v = xf_compose(v, gen_step(P, t.x, ir.x, qi.x, qa.x, ra.x));
            v = xf_compose(v, gen_step(P, t.y, ir.y, qi.y, qa.y, ra.y));
            v = xf_compose(v, gen_step(P, t.z, ir.z, qi.z, qa.z, ra.z));
            v = xf_compose(v, gen_step(P, t.w, ir.w, qi.w, qa.w, ra.w));
        }
    } else {
        for (int j = 0; j < CHUNK; ++j) {
            int i = base + j;
            if (i < N)
                v = xf_compose(v, gen_step(P, To[i], Irr[i], Qi[i], Qa[i], Ra[i]));
        }
    }
    return v;
}

// LDS helpers — stride 7 floats to avoid bank conflicts (gcd(7,32)=1)
__device__ __forceinline__ void sm_store(float* sm, int i, const Xf& v) {
    float* b = sm + i * 7;
    b[0] = v.p; b[1] = v.q; b[2] = v.r; b[3] = v.s; b[4] = v.u; b[5] = v.v;
}
__device__ __forceinline__ Xf sm_load(const float* sm, int i) {
    const float* b = sm + i * 7;
    Xf v; v.p = b[0]; v.q = b[1]; v.r = b[2]; v.s = b[3]; v.u = b[4]; v.v = b[5];
    return v;
}

// Inclusive Hillis-Steele scan over BLOCK transforms; sm holds inclusive values on exit
__device__ __forceinline__ Xf block_scan(Xf v, float* sm) {
    const int t = threadIdx.x;
    sm_store(sm, t, v);
    __syncthreads();
    for (int off = 1; off < BLOCK; off <<= 1) {
        Xf e;
        bool has = (t >= off);
        if (has) e = sm_load(sm, t - off);
        __syncthreads();
        if (has) { v = xf_compose(e, v); sm_store(sm, t, v); }
        __syncthreads();
    }
    return v;
}

__global__ __launch_bounds__(BLOCK) void k_blocksum(
    const float* __restrict__ To, const float* __restrict__ Irr,
    const float* __restrict__ Qi, const float* __restrict__ Qa,
    const float* __restrict__ Ra,
    const float* pRie, const float* pRea, const float* pCin, const float* pCen,
    const float* pAsi, const float* pAse, const float* pAii, const float* pAie,
    Xf* __restrict__ blkX, int N)
{
    Par P = make_par(pRie, pRea, pCin, pCen, pAsi, pAse, pAii, pAie);
    int base = blockIdx.x * SPAN + threadIdx.x * CHUNK;
    Xf v = chunk_xf(P, To, Irr, Qi, Qa, Ra, base, N);
    __shared__ float sm[BLOCK * 7];
    v = block_scan(v, sm);
    if (threadIdx.x == BLOCK - 1) blkX[blockIdx.x] = v;
}

__global__ __launch_bounds__(BLOCK) void k_mid(
    const Xf* __restrict__ blkX, float2* __restrict__ blkSt,
    const float* pTin0, int NB)
{
    const int t = threadIdx.x;
    const int ser = (NB + BLOCK - 1) / BLOCK;
    const int base = t * ser;
    Xf acc = xf_id();
    for (int j = 0; j < ser; ++j) {
        int i = base + j;
        if (i < NB) acc = xf_compose(acc, blkX[i]);
    }
    __shared__ float sm[BLOCK * 7];
    block_scan(acc, sm);
    Xf E = xf_id();
    if (t > 0) E = sm_load(sm, t - 1);
    float T0 = *pTin0;
    float x0 = E.p * T0 + E.q * T0 + E.u;
    float x1 = E.r * T0 + E.s * T0 + E.v;
    for (int j = 0; j < ser; ++j) {
        int i = base + j;
        if (i < NB) {
            blkSt[i] = make_float2(x0, x1);
            Xf T = blkX[i];
            float n0 = T.p * x0 + T.q * x1 + T.u;
            float n1 = T.r * x0 + T.s * x1 + T.v;
            x0 = n0; x1 = n1;
        }
    }
}

__global__ __launch_bounds__(BLOCK) void k_emit(
    const float* __restrict__ To, const float* __restrict__ Irr,
    const float* __restrict__ Qi, const float* __restrict__ Qa,
    const float* __restrict__ Ra,
    const float* pRie, const float* pRea, const float* pCin, const float* pCen,
    const float* pAsi, const float* pAse, const float* pAii, const float* pAie,
    const float2* __restrict__ blkSt, float* __restrict__ out, int N)
{
    Par P = make_par(pRie, pRea, pCin, pCen, pAsi, pAse, pAii, pAie);
    const int t = threadIdx.x;
    int base = blockIdx.x * SPAN + t * CHUNK;
    Xf v = chunk_xf(P, To, Irr, Qi, Qa, Ra, base, N);
    __shared__ float sm[BLOCK * 7];
    block_scan(v, sm);
    Xf E = xf_id();
    if (t > 0) E = sm_load(sm, t - 1);
    float2 B = blkSt[blockIdx.x];
    float x0 = E.p * B.x + E.q * B.y + E.u;
    float x1 = E.r * B.x + E.s * B.y + E.v;

    if (base + CHUNK <= N) {
#pragma unroll
        for (int g = 0; g < CHUNK / 4; ++g) {
            const int o = base + g * 4;
            float4 tt = *(const float4*)(To + o);
            float4 ir = *(const float4*)(Irr + o);
            float4 qi = *(const float4*)(Qi + o);
            float4 qa = *(const float4*)(Qa + o);
            float4 ra = *(const float4*)(Ra + o);
            float4 ov;
            {
                Xf T = gen_step(P, tt.x, ir.x, qi.x, qa.x, ra.x);
                float n0 = T.p * x0 + T.q * x1 + T.u;
                float n1 = T.r * x0 + T.s * x1 + T.v;
                x0 = n0; x1 = n1; ov.x = n1;
            }
            {
                Xf T = gen_step(P, tt.y, ir.y, qi.y, qa.y, ra.y);
                float n0 = T.p * x0 + T.q * x1 + T.u;
                float n1 = T.r * x0 + T.s * x1 + T.v;
                x0 = n0; x1 = n1; ov.y = n1;
            }
            {
                Xf T = gen_step(P, tt.z, ir.z, qi.z, qa.z, ra.z);
                float n0 = T.p * x0 + T.q * x1 + T.u;
                float n1 = T.r * x0 + T.s * x1 + T.v;
                x0 = n0; x1 = n1; ov.z = n1;
            }
            {
                Xf T = gen_step(P, tt.w, ir.w, qi.w, qa.w, ra.w);
                float n0 = T.p * x0 + T.q * x1 + T.u;
                float n1 = T.r * x0 + T.s * x1 + T.v;
                x0 = n0; x1 = n1; ov.w = n1;
            }
            *(float4*)(out + o) = ov;
        }
    } else {
        for (int j = 0; j < CHUNK; ++j) {
            int i = base + j;
            if (i < N) {
                Xf T = gen_step(P, To[i], Irr[i], Qi[i], Qa[i], Ra[i]);
                float n0 = T.p * x0 + T.q * x1 + T.u;
                float n1 = T.r * x0 + T.s * x1 + T.v;
                x0 = n0; x1 = n1;
                out[i] = n1;
            }
        }
    }
}

extern "C" void kernel_launch(void* const* d_in, const int* in_sizes, int n_in,
                              void* d_out, int out_size, void* d_ws, size_t ws_size,
                              hipStream_t stream)
{
    const float* pRie = (const float*)d_in[0];
    const float* pRea = (const float*)d_in[1];
    const float* pCin = (const float*)d_in[2];
    const float* pCen = (const float*)d_in[3];
    const float* pAsi = (const float*)d_in[4];
    const float* pAse = (const float*)d_in[5];
    const float* pAii = (const float*)d_in[6];
    const float* pAie = (const float*)d_in[7];
    const float* pTin0 = (const float*)d_in[8];
    const float* To  = (const float*)d_in[9];
    const float* Irr = (const float*)d_in[10];
    const float* Qi  = (const float*)d_in[11];
    const float* Qa  = (const float*)d_in[12];
    const float* Ra  = (const float*)d_in[13];
    const int N = in_sizes[9];
    if (N <= 0) return;

    const int NCH = (N + CHUNK - 1) / CHUNK;
    const int NB  = (NCH + BLOCK - 1) / BLOCK;

    Xf* blkX = (Xf*)d_ws;
    size_t off = ((size_t)NB * sizeof(Xf) + 255) & ~(size_t)255;
    float2* blkSt = (float2*)((char*)d_ws + off);

    k_blocksum<<<NB, BLOCK, 0, stream>>>(To, Irr, Qi, Qa, Ra,
        pRie, pRea, pCin, pCen, pAsi, pAse, pAii, pAie, blkX, N);
    k_mid<<<1, BLOCK, 0, stream>>>(blkX, blkSt, pTin0, NB);
    k_emit<<<NB, BLOCK, 0, stream>>>(To, Irr, Qi, Qa, Ra,
        pRie, pRea, pCin, pCen, pAsi, pAse, pAii, pAie, blkSt, out_size > 0 ? (float*)d_out : (float*)d_out, N);
}